// Round 8
// baseline (182.544 us; speedup 1.0000x reference)
//
#include <hip/hip_runtime.h>
#include <hip/hip_bf16.h>

// MoE MLP top-1 + shared expert. T=2048 H=768 I=2048 E=8, f32 in/out.
// R8: chunk order changed to (e, kc, nt) so each 32-row weight slab is
//     contiguous in src f32 AND dst bf16. wconv = per-slab pipeline:
//     gll16-stage [8 x 1024] f32 panels (1KB-contiguous reads), counted
//     vmcnt + raw barriers (never drain mid-loop), LDS transpose-convert,
//     256B-contiguous bf16 writes. Router fused. Stages: stride-only change.
// Chunk = 128 n x 32 k bf16 (4096 u16 = 8KB), in-chunk addr:
//   ((n>>4)&7)*512 + ((k>>3)&3)*128 + (n&15)*8 + (k&7)
// gll16 copies chunks linearly; MFMA fragment reads are linear-in-lane.

#define TT 2048
#define HH 768
#define II 2048
#define NE 8
#define RSLOTS 3072   // routed padded slots (24 tiles of 128)
#define WBLK 1008     // wconv slabs: 432 gate/up + 576 down

typedef unsigned short u16;
typedef unsigned int u32;
typedef short s16x8 __attribute__((ext_vector_type(8)));
typedef u16 u16x8 __attribute__((ext_vector_type(8)));
typedef float f32x4 __attribute__((ext_vector_type(4)));

__device__ __forceinline__ u16 f2bf(float f) {  // f32 -> bf16 RNE
  u32 u = __builtin_bit_cast(u32, f);
  return (u16)((u + 0x7FFFu + ((u >> 16) & 1u)) >> 16);
}

typedef __attribute__((address_space(3))) u32 lds_u32;
typedef const __attribute__((address_space(1))) u32 glb_u32;
__device__ __forceinline__ void gll16(const void* g, void* l) {
  // global src per-lane; LDS dest wave-uniform base + lane*16 (linear)
  __builtin_amdgcn_global_load_lds((glb_u32*)g,
                                   (lds_u32*)(u32)(unsigned long long)l, 16, 0, 0);
}

// ---------------- fused wconv + router ----------------
// slabs: id<432: gate/up (em=id/24: e=em>>1, mat=em&1; kc=id%24) [32k x 2048n]
//        id>=432: down (e=(id-432)/64, kc=(id-432)%64)           [32k x 768n]
// dst slabs contiguous: Wg/Wu: ((e*24+kc)*16 + nt)*4096 ; Wd: ((e*64+kc)*6+nt)*4096
__global__ __launch_bounds__(256) void wconv_router_kernel(
    const float* __restrict__ gate_w, const float* __restrict__ up_w,
    const float* __restrict__ down_w, const float* __restrict__ sh_gate,
    const float* __restrict__ sh_up, const float* __restrict__ sh_down,
    u16* __restrict__ Wgt, u16* __restrict__ Wut, u16* __restrict__ Wdt,
    const float* __restrict__ x, const float* __restrict__ rw,
    float* __restrict__ score, int* __restrict__ list, int* __restrict__ cnt,
    float* __restrict__ probsum) {
  __shared__ float fbuf[2][8 * 1024];  // 64 KB (down slabs use 8*768 of each)
  const int t = threadIdx.x, wid = t >> 6, lane = t & 63;

  if (blockIdx.x >= WBLK) {
    // ---- router: one wave per token ----
    const int tok = (int)(((blockIdx.x - WBLK) * 256 + t) >> 6);
    if (tok >= TT) return;
    double acc[NE];
#pragma unroll
    for (int e = 0; e < NE; ++e) acc[e] = 0.0;
    const float* xr = x + (size_t)tok * HH;
    for (int h = lane; h < HH; h += 64) {
      const double xv = (double)xr[h];
#pragma unroll
      for (int e = 0; e < NE; ++e) acc[e] += xv * (double)rw[h * NE + e];
    }
#pragma unroll
    for (int off = 32; off > 0; off >>= 1) {
#pragma unroll
      for (int e = 0; e < NE; ++e) acc[e] += __shfl_xor(acc[e], off);
    }
    if (lane == 0) {
      int best = 0;
#pragma unroll
      for (int e = 1; e < NE; ++e)
        if (acc[e] > acc[best]) best = e;  // strict > == first-max (jnp.argmax)
      const float sc = 1.0f / (1.0f + __expf((float)(-acc[best])));
      score[tok] = sc;
      const int pos = atomicAdd(&cnt[best], 1);
      list[best * TT + pos] = tok;
      atomicAdd(&probsum[best], sc);
    }
    return;
  }

  // ---- wconv slab ----
  const int id = blockIdx.x;
  const bool gu = (id < 432);
  const float* srcs;
  u16* dsts;
  int W, niter, rowstride, nst;
  if (gu) {
    const int em = id / 24, kc = id % 24;
    const int e = em >> 1;
    const float* base = (em & 1) ? (e < 8 ? up_w + (size_t)e * HH * II : sh_up)
                                 : (e < 8 ? gate_w + (size_t)e * HH * II : sh_gate);
    srcs = base + (size_t)(kc * 32) * II;
    dsts = ((em & 1) ? Wut : Wgt) + ((size_t)(e * 24 + kc) * 16) * 4096;
    W = 1024; niter = 8; rowstride = II; nst = 4;   // 8 nt-chunks per panel
  } else {
    const int id2 = id - 432, e = id2 / 64, kc = id2 % 64;
    srcs = ((e < 8) ? down_w + (size_t)e * II * HH : sh_down) + (size_t)(kc * 32) * HH;
    dsts = Wdt + ((size_t)(e * 64 + kc) * 6) * 4096;
    W = 768; niter = 4; rowstride = HH; nst = 3;    // 6 nt-chunks per panel
  }

  // panel it: rows rowoff..+8 (wave owns 2), cols coloff..+W; 1KB-contig gll16
#define ISSUE(it, buf)                                                         \
  {                                                                            \
    const int rowoff_ = gu ? ((it) >> 1) * 8 : (it) * 8;                       \
    const int coloff_ = gu ? ((it) & 1) * 1024 : 0;                            \
    const int nseg_ = W >> 8;                                                  \
    for (int rr = 0; rr < 2; ++rr) {                                           \
      const int r_ = 2 * wid + rr;                                             \
      const float* sp_ =                                                       \
          srcs + (size_t)(rowoff_ + r_) * rowstride + coloff_ + lane * 4;      \
      float* lp_ = &fbuf[buf][r_ * W];                                         \
      for (int s = 0; s < nseg_; ++s) gll16(sp_ + s * 256, lp_ + s * 256);     \
    }                                                                          \
  }

  ISSUE(0, 0)
  ISSUE(1, 1)
  for (int it = 0; it < niter; ++it) {
    const int buf = it & 1;
    if (it < niter - 1) {  // own panel done; next panel (8 or 6 loads) in flight
      if (gu) asm volatile("s_waitcnt vmcnt(8)" ::: "memory");
      else    asm volatile("s_waitcnt vmcnt(6)" ::: "memory");
    } else {
      asm volatile("s_waitcnt vmcnt(0)" ::: "memory");
    }
    __builtin_amdgcn_s_barrier();
    // transpose-convert panel: 256B-contiguous dst pieces
    const int koct = gu ? (it >> 1) : it;
    const int ntoff = gu ? (it & 1) * 8 : 0;
    for (int s = 0; s < nst; ++s) {
      const int o = s * 256 + t;
      const int fr = o & 15, nq = (o >> 4) & 7, ntl = o >> 7;
      const float* lp = &fbuf[buf][ntl * 128 + nq * 16 + fr];
      u16x8 w;
#pragma unroll
      for (int j = 0; j < 8; ++j) w[j] = f2bf(lp[j * W]);
      *reinterpret_cast<u16x8*>(
          &dsts[(size_t)(ntoff + ntl) * 4096 + nq * 512 + koct * 128 + fr * 8]) = w;
    }
    __builtin_amdgcn_s_barrier();
    if (it + 2 < niter) ISSUE(it + 2, buf)
  }
#undef ISSUE
}

// ---------------- plan: padded segments + tile->expert + loss ----------------
__global__ void plan_kernel(const int* __restrict__ cnt, const float* __restrict__ probsum,
                            int* __restrict__ meta, float* __restrict__ out) {
  if (threadIdx.x == 0) {
    int S = 0;
    for (int e = 0; e < NE; ++e) {
      meta[e] = S;
      const int pad = (cnt[e] + 127) & ~127;
      for (int t = S >> 7; t < (S + pad) >> 7; ++t) meta[16 + t] = e;
      S += pad;
    }
    meta[8] = S;
    for (int t = S >> 7; t < 24; ++t) meta[16 + t] = 0;
    float s = 0.0f;
    for (int e = 0; e < NE; ++e) s += (float)cnt[e] * probsum[e];
    out[(size_t)TT * HH] = s * (0.001f * (float)NE / ((float)TT * (float)TT));
  }
}

// ---------------- gather: x -> tiled bf16 Xc (+tokmap) ----------------
__global__ __launch_bounds__(256) void gather_kernel(
    const float* __restrict__ x, const float* __restrict__ score,
    const int* __restrict__ list, const int* __restrict__ cnt,
    const int* __restrict__ meta, u16* __restrict__ Xc, int* __restrict__ tokmap) {
  const int task = blockIdx.x * 4 + (threadIdx.x >> 6);
  const int lane = threadIdx.x & 63;
  const int pb = task / 24;  // 16-row block, 0..319
  const int c = task % 24;   // k chunk
  const int fq = lane >> 4, fr = lane & 15;
  const int p = pb * 16 + fr;
  int tok;
  float sc;
  if (p >= RSLOTS) {
    tok = p - RSLOTS;
    sc = 1.0f;
  } else {
    const int e = meta[16 + (p >> 7)];
    const int idx = p - meta[e];
    tok = (idx >= 0 && idx < cnt[e]) ? list[e * TT + idx] : -1;
    sc = (tok >= 0) ? score[tok] : 0.0f;
  }
  u16x8 w = {0, 0, 0, 0, 0, 0, 0, 0};
  if (tok >= 0) {
    const float* xp = x + (size_t)tok * HH + c * 32 + fq * 8;
    const f32x4 a = *reinterpret_cast<const f32x4*>(xp);
    const f32x4 b = *reinterpret_cast<const f32x4*>(xp + 4);
#pragma unroll
    for (int j = 0; j < 4; ++j) {
      w[j] = f2bf(a[j] * sc);
      w[j + 4] = f2bf(b[j] * sc);
    }
  }
  *reinterpret_cast<u16x8*>(&Xc[((size_t)(pb >> 3) * 24 + c) * 4096 + (pb & 7) * 512 +
                                lane * 8]) = w;
  if (c == 0 && fq == 0) tokmap[p] = tok;
}

// ---------------- stage A: P = silu(Xc Wg) * (Xc Wu) ----------------
// grid (16 nt, 40 mty): mty<24 routed (early-exit past Rp), >=24 shared (e=8).
__global__ __launch_bounds__(256, 2) void stageA_kernel(
    const u16* __restrict__ Xc, const int* __restrict__ meta,
    const u16* __restrict__ Wgt, const u16* __restrict__ Wut, u16* __restrict__ P) {
  const int mty = blockIdx.y, nt = blockIdx.x;
  int e;
  if (mty < 24) {
    if (mty * 128 >= meta[8]) return;
    e = meta[16 + mty];
  } else {
    e = 8;
  }
  // chunk (e, c, nt): stride between c = 16*4096
  const u16* wg = Wgt + ((size_t)e * 24 * 16 + nt) * 4096;
  const u16* wu = Wut + ((size_t)e * 24 * 16 + nt) * 4096;
  const u16* xa = Xc + (size_t)mty * 24 * 4096;

  __shared__ u16 As[2][4096], Bgs[2][4096], Bus[2][4096];

  const int tid = threadIdx.x, lane = tid & 63, wid = tid >> 6;
  const int fr = lane & 15, fq = lane >> 4;
  const int wm4 = (wid >> 1) * 4;  // row 16-block base
  const int wn4 = (wid & 1) * 4;   // col 16-block base
  const int wn = (wid & 1) * 64;
  const int ncol = nt * 128;
  const int so = wid * 1024 + lane * 8;  // gll global src offset (u16)
  const int sl = wid * 1024;             // gll LDS dst offset (u16), wave-uniform

  f32x4 accg[4][4], accu[4][4];
#pragma unroll
  for (int i = 0; i < 4; ++i)
#pragma unroll
    for (int j = 0; j < 4; ++j) {
      accg[i][j] = f32x4{0.f, 0.f, 0.f, 0.f};
      accu[i][j] = f32x4{0.f, 0.f, 0.f, 0.f};
    }

  // full chunk = 4096 u16; 4 waves x 2 gll16 x 512 u16 each
#define STAGE(c, buf)                                                 \
  {                                                                   \
    gll16(xa + (size_t)(c) * 4096 + so, &As[buf][sl]);                \
    gll16(xa + (size_t)(c) * 4096 + so + 512, &As[buf][sl + 512]);    \
    gll16(wg + (size_t)(c) * 65536 + so, &Bgs[buf][sl]);              \
    gll16(wg + (size_t)(c) * 65536 + so + 512, &Bgs[buf][sl + 512]);  \
    gll16(wu + (size_t)(c) * 65536 + so, &Bus[buf][sl]);              \
    gll16(wu + (size_t)(c) * 65536 + so + 512, &Bus[buf][sl + 512]);  \
  }

  STAGE(0, 0)
  __syncthreads();
  int cur = 0;
  for (int c = 0; c < 24; ++c) {
    if (c < 23) STAGE(c + 1, cur ^ 1)
    s16x8 af[4], bg[4], bu[4];
#pragma unroll
    for (int i = 0; i < 4; ++i) {
      af[i] = *reinterpret_cast<const s16x8*>(&As[cur][(wm4 + i) * 512 + fq * 128 + fr * 8]);
      bg[i] = *reinterpret_cast<const s16x8*>(&Bgs[cur][(wn4 + i) * 512 + fq * 128 + fr * 8]);
      bu[i] = *reinterpret_cast<const s16x8*>(&Bus[cur][(wn4 + i) * 512 + fq * 128 + fr * 8]);
    }
#pragma unroll
    for (int j = 0; j < 4; ++j)
#pragma unroll
      for (int i = 0; i < 4; ++i) {
        accg[i][j] = __builtin_amdgcn_mfma_f32_16x16x32_bf16(af[i], bg[j], accg[i][j], 0, 0, 0);
        accu[i][j] = __builtin_amdgcn_mfma_f32_16x16x32_bf16(af[i], bu[j], accu[i][j], 0, 0, 0);
      }
    __syncthreads();
    cur ^= 1;
  }
#undef STAGE

  // epilogue: silu(g)*u -> P tiled bf16 (C/D: row=fq*4+reg, col=fr)
#pragma unroll
  for (int i = 0; i < 4; ++i)
#pragma unroll
    for (int cc = 0; cc < 4; ++cc) {
      const int rlo = fq * 4 + cc;  // row & 15 within 16-block (wm4+i)
#pragma unroll
      for (int j = 0; j < 4; ++j) {
        const int k = ncol + wn + j * 16 + fr;  // global i-col
        const float gv = accg[i][j][cc];
        const float val = (gv / (1.0f + __expf(-gv))) * accu[i][j][cc];
        P[((size_t)mty * 64 + (k >> 5)) * 4096 + (size_t)(wm4 + i) * 512 +
          ((k >> 3) & 3) * 128 + rlo * 8 + (k & 7)] = f2bf(val);
      }
    }
}

// ---------------- stage B: out += P Wd (atomicAdd, out pre-zeroed) ----------------
// grid (6 nt, 40 mty); each out element gets one shared + at most one routed add.
__global__ __launch_bounds__(256, 2) void stageB_kernel(
    const u16* __restrict__ P, const int* __restrict__ meta,
    const int* __restrict__ tokmap, const u16* __restrict__ Wdt,
    float* __restrict__ out) {
  const int mty = blockIdx.y, nt = blockIdx.x;
  int e;
  if (mty < 24) {
    if (mty * 128 >= meta[8]) return;
    e = meta[16 + mty];
  } else {
    e = 8;
  }
  // chunk (e, c, nt): stride between c = 6*4096
  const u16* wd = Wdt + ((size_t)e * 64 * 6 + nt) * 4096;
  const u16* pa = P + (size_t)mty * 64 * 4096;

  __shared__ u16 As[2][4096], Bs[2][4096];

  const int tid = threadIdx.x, lane = tid & 63, wid = tid >> 6;
  const int fr = lane & 15, fq = lane >> 4;
  const int wm4 = (wid >> 1) * 4;
  const int wn4 = (wid & 1) * 4;
  const int wm = (wid >> 1) * 64;
  const int wn = (wid & 1) * 64;
  const int ncol = nt * 128;
  const int so = wid * 1024 + lane * 8;
  const int sl = wid * 1024;

  f32x4 acc[4][4];
#pragma unroll
  for (int i = 0; i < 4; ++i)
#pragma unroll
    for (int j = 0; j < 4; ++j) acc[i][j] = f32x4{0.f, 0.f, 0.f, 0.f};

#define STAGEB(c, buf)                                                \
  {                                                                   \
    gll16(pa + (size_t)(c) * 4096 + so, &As[buf][sl]);                \
    gll16(pa + (size_t)(c) * 4096 + so + 512, &As[buf][sl + 512]);    \
    gll16(wd + (size_t)(c) * 24576 + so, &Bs[buf][sl]);               \
    gll16(wd + (size_t)(c) * 24576 + so + 512, &Bs[buf][sl + 512]);   \
  }

  STAGEB(0, 0)
  __syncthreads();
  int cur = 0;
  for (int c = 0; c < 64; ++c) {
    if (c < 63) STAGEB(c + 1, cur ^ 1)
    s16x8 af[4], bf[4];
#pragma unroll
    for (int i = 0; i < 4; ++i) {
      af[i] = *reinterpret_cast<const s16x8*>(&As[cur][(wm4 + i) * 512 + fq * 128 + fr * 8]);
      bf[i] = *reinterpret_cast<const s16x8*>(&Bs[cur][(wn4 + i) * 512 + fq * 128 + fr * 8]);
    }
#pragma unroll
    for (int j = 0; j < 4; ++j)
#pragma unroll
      for (int i = 0; i < 4; ++i)
        acc[i][j] = __builtin_amdgcn_mfma_f32_16x16x32_bf16(af[i], bf[j], acc[i][j], 0, 0, 0);
    __syncthreads();
    cur ^= 1;
  }
#undef STAGEB

#pragma unroll
  for (int i = 0; i < 4; ++i)
#pragma unroll
    for (int cc = 0; cc < 4; ++cc) {
      const int p = mty * 128 + wm + i * 16 + fq * 4 + cc;
      const int tok = tokmap[p];
      if (tok >= 0) {
#pragma unroll
        for (int j = 0; j < 4; ++j)
          atomicAdd(&out[(size_t)tok * HH + ncol + wn + j * 16 + fr], acc[i][j][cc]);
      }
    }
}

// ---------------- launcher ----------------
extern "C" void kernel_launch(void* const* d_in, const int* in_sizes, int n_in,
                              void* d_out, int out_size, void* d_ws, size_t ws_size,
                              hipStream_t stream) {
  (void)in_sizes; (void)n_in; (void)ws_size;
  const float* x = (const float*)d_in[0];
  const float* rw = (const float*)d_in[1];
  const float* gate_w = (const float*)d_in[2];
  const float* up_w = (const float*)d_in[3];
  const float* down_w = (const float*)d_in[4];
  const float* sh_gate = (const float*)d_in[5];
  const float* sh_up = (const float*)d_in[6];
  const float* sh_down = (const float*)d_in[7];
  float* out = (float*)d_out;

  char* ws = (char*)d_ws;
  size_t off = 0;
  u16* Xc = (u16*)(ws + off);  off += (size_t)(RSLOTS + TT) * HH * sizeof(u16);   // 7.9MB
  u16* P = (u16*)(ws + off);   off += (size_t)(RSLOTS + TT) * II * sizeof(u16);   // 21MB
  u16* Wgt = (u16*)(ws + off); off += (size_t)9 * 16 * 24 * 4096 * sizeof(u16);   // 28.3MB
  u16* Wut = (u16*)(ws + off); off += (size_t)9 * 16 * 24 * 4096 * sizeof(u16);   // 28.3MB
  u16* Wdt = (u16*)(ws + off); off += (size_t)9 * 6 * 64 * 4096 * sizeof(u16);    // 28.3MB
  float* score = (float*)(ws + off);   off += TT * sizeof(float);
  int* list = (int*)(ws + off);        off += (size_t)NE * TT * sizeof(int);
  int* cnt = (int*)(ws + off);         off += 16 * sizeof(int);
  float* probsum = (float*)(ws + off); off += 16 * sizeof(float);
  int* meta = (int*)(ws + off);        off += 64 * sizeof(int);
  int* tokmap = (int*)(ws + off);

  hipMemsetAsync(d_out, 0, (size_t)out_size * sizeof(float), stream);
  hipMemsetAsync(cnt, 0, 16 * sizeof(int) + 16 * sizeof(float), stream);
  wconv_router_kernel<<<dim3(WBLK + 512), dim3(256), 0, stream>>>(
      gate_w, up_w, down_w, sh_gate, sh_up, sh_down, Wgt, Wut, Wdt, x, rw, score,
      list, cnt, probsum);
  plan_kernel<<<dim3(1), dim3(64), 0, stream>>>(cnt, probsum, meta, out);
  gather_kernel<<<dim3(1920), dim3(256), 0, stream>>>(x, score, list, cnt, meta, Xc,
                                                      tokmap);
  stageA_kernel<<<dim3(16, 40, 1), dim3(256), 0, stream>>>(Xc, meta, Wgt, Wut, P);
  stageB_kernel<<<dim3(6, 40, 1), dim3(256), 0, stream>>>(P, meta, tokmap, Wdt, out);
}